// Round 8
// baseline (174.989 us; speedup 1.0000x reference)
//
#include <hip/hip_runtime.h>
#include <math.h>

// ---------------------------------------------------------------------------
// TwoDimEquivalent: B=8192 independent nonlinear scans of length T=2048.
// R13: ANALYTIC g(s) -- zero LDS ops in the step loop.
//   Model (fits R7/R9/R10/R11/R12): the divergent ds_read_b64 LUT gather
//   saturates the per-CU LDS pipe (~60 cyc/wave-gather x 8 waves/CU = ~500
//   cyc/step-round = observed 516). R12's removal of the (pipelined) u-read
//   was null because only the gather's pipe occupancy matters. Fix: evaluate
//   gauss_int in VALU. g(d)=E[sech^2(dZ)]; h(y)=g/y with y=1/sqrt(1+(pi/2)s)
//   is analytic on y in [0.099,1] (pi/2 makes the asymptote exact: h->1 both
//   ends); Chebyshev deg-15 interp error ~3e-5 (Bernstein rho~1.9). Coeffs
//   computed EXACTLY in setup (double GL-64 at 16 Chebyshev nodes + explicit
//   DCT, no solver), broadcast via ws; eval = v_rsq + two parallel 8-term
//   Clenshaws (even/odd in u=2t^2-1; S_E=e0+u*b1-b2, S_O=b0-b1 for the
//   V-basis T_{2m+1}(t)=t*V_m(u), V_{m+1}=2uV_m-V_{m-1}).
//  * Wave-autonomous (R11/R12 kept): wave owns 64 rows, private [64][33]
//    LDS staging, batched u READBACK, NO barriers at all now (s_tab gone).
//  * 16 chunks x 128 steps, 128-step warmup (bytes/accuracy unchanged).
//  * z: zz[64] regs, flushed through sb (2x32-col transpose, 2-way banks).
// History: R5 151.9 (warm 57). R7 more waves: per-step wall improved ->
// saturating a serializer. R8: not read-BW-bound; graded runs ~2.5x-degraded
// env. R9 counted barriers: cold-dispatch fixed. R10 ILP-2: fewer waves
// regress. R11 no-barrier: null. R12 one-DS/step: null -> gather-pipe model.
// R13 predict: warm 22-32, VALUBusy 75-95%, conflicts <0.3M, graded 60-90.
// ---------------------------------------------------------------------------

#define Bsz   8192
#define Tlen  2048
#define TP1   2049
#define NQ    64
#define NCH   16                  // Chebyshev coeff count (deg 15)
#define CHUNKS 16
#define CLEN  128
#define WARM  128
#define BLOCK 256
#define SIM_GRID (32 * CHUNKS)    // 512: 32 row-blocks(256) x 16 chunks
#define SROW  33                  // staging row stride (floats): banks 2-way

#define PI_D 3.14159265358979323846
#define B_D  1.5707963267948966    // pi/2: exact asymptote normalizer
// y0 = 1/sqrt(1+64*B_D); interval [y0,1] mapped by y = D_YM + D_YR*x
#define D_YM 0.5496216
#define D_YR 0.4503784

// Intra-wave DS fence: all my ds ops complete; compiler may not reorder.
__device__ __forceinline__ void ds_fence() {
    asm volatile("s_waitcnt lgkmcnt(0)" ::: "memory");
}

// --------- setup: exact GL-64 -> h at 16 Chebyshev nodes -> DCT ------------
__global__ __launch_bounds__(256) void setup_kernel(float* __restrict__ ws,
                                                    float* __restrict__ out) {
    const int tid = threadIdx.x;
    if (blockIdx.x == 0) {
        __shared__ double dxs[NQ], dwe[NQ], dh[NCH];
        __shared__ double inv[NQ + 1];
        if (tid <= NQ) inv[tid] = (tid == 0) ? 0.0 : 1.0 / (double)tid;
        __syncthreads();
        if (tid < NQ) {
            // Newton on P_64: guess err ~3e-4 -> 3 updates reach ~1e-15,
            // 4th pass evaluates pp at converged z (no update).
            double z = cos(PI_D * (tid + 0.75) / (NQ + 0.5));
            double p1 = 1.0, p2 = 0.0, pp = 1.0;
            for (int it = 0; it < 4; ++it) {
                p1 = 1.0; p2 = 0.0;
                for (int j = 1; j <= NQ; ++j) {
                    double p3 = p2; p2 = p1;
                    p1 = ((2.0 * j - 1.0) * z * p2 - (j - 1.0) * p3) * inv[j];
                }
                pp = NQ * (z * p1 - p2) / (z * z - 1.0);
                if (it < 3) z -= p1 / pp;
            }
            double w  = 2.0 / ((1.0 - z * z) * pp * pp);
            double xs = z * 5.0;                   // node scaled to [-5,5]
            dxs[tid] = xs;
            dwe[tid] = w * 5.0 * exp(-0.5 * xs * xs) * 0.3989422804014327;
        }
        __syncthreads();
        if (tid < NCH) {                           // h at Chebyshev node k
            double th = PI_D * (tid + 0.5) / NCH;
            double yk = D_YM + D_YR * cos(th);
            double sk = (1.0 / (yk * yk) - 1.0) / B_D;
            double dk = sqrt(sk);
            double acc = 0.0;
            for (int q = 0; q < NQ; ++q) {         // exact 64-pt GL sum
                double t0 = tanh(dk * dxs[q]);
                acc += dwe[q] * (1.0 - t0 * t0);
            }
            dh[tid] = acc / yk;                    // h = g * sqrt(1+B*s)
        }
        __syncthreads();
        if (tid < NCH) {                           // DCT -> Chebyshev coeffs
            double cj = 0.0;
            for (int k = 0; k < NCH; ++k)
                cj += dh[k] * cos((double)tid * PI_D * (k + 0.5) / NCH);
            cj *= 2.0 / NCH;
            if (tid == 0) cj *= 0.5;
            ws[tid] = (float)cj;
        }
    }
    const int j = blockIdx.x * 256 + tid;          // grid 32x256 = 8192
    out[(size_t)j * TP1] = 0.0f;                   // z_hist[:,0] = 0
}

// ------------------------------ main scan ----------------------------------
// Pure-VALU step: no LDS access. cA..cD hold the 16 Chebyshev coefficients
// (even terms in .x/.z, odd terms in .y/.w).
__device__ __forceinline__ float step_one(float uu, float& k1, float& k2,
                                          float& v, float4 cA, float4 cB,
                                          float4 cC, float4 cD) {
    float s  = fmaf(k1, k1, fmaf(k2, k2, uu * uu));       // delta^2
    s        = fminf(s, 63.9f);                           // poly domain
    float ys = fmaf((float)B_D, s, 1.0f);
    float y;                                              // 1/sqrt(1+B*s)
    asm("v_rsq_f32 %0, %1" : "=v"(y) : "v"(ys));
    float t  = fmaf(y, (float)(1.0 / D_YR), -(float)(D_YM / D_YR));
    float u2 = fmaf(t + t, t, -1.0f);                     // 2t^2-1
    float tu = u2 + u2;
    // even: sum e_m T_m(u2), e_m = c_{2m}
    float b7 = cD.z;
    float b6 = fmaf(tu, b7, cD.x);
    float b5 = fmaf(tu, b6, cC.z - b7);
    float b4 = fmaf(tu, b5, cC.x - b6);
    float b3 = fmaf(tu, b4, cB.z - b5);
    float b2 = fmaf(tu, b3, cB.x - b4);
    float b1 = fmaf(tu, b2, cA.z - b3);
    float SE = fmaf(u2, b1, cA.x - b2);
    // odd: t * sum d_m V_m(u2), d_m = c_{2m+1}; V0=1, V1=2u-1 -> S=b0-b1
    float a7 = cD.w;
    float a6 = fmaf(tu, a7, cD.y);
    float a5 = fmaf(tu, a6, cC.w - a7);
    float a4 = fmaf(tu, a5, cC.y - a6);
    float a3 = fmaf(tu, a4, cB.w - a5);
    float a2 = fmaf(tu, a3, cB.y - a4);
    float a1 = fmaf(tu, a2, cA.w - a3);
    float a0 = fmaf(tu, a1, cA.y - a2);
    float g  = fmaf(t, a0 - a1, SE) * y;                  // gauss_int
    float gv  = g * v;
    float nk1 = fmaf(k1, fmaf(0.2f, g, 0.8f), 0.10f * gv);
    float nk2 = fmaf(k2, fmaf(0.1f, g, 0.8f), 0.38f * gv);
    v  = fmaf(0.2f, uu - v, v);
    k1 = nk1; k2 = nk2;
    return fmaf(2.8f, nk1, -2.2f * nk2);
}

// Load next window (8 float4 = 8 rows x 128 B coalesced segments)
#define GLOAD(G, t) { _Pragma("unroll")                                       \
    for (int r = 0; r < 8; ++r)                                               \
        G[r] = *(const float4*)(up + (size_t)r * 8 * Tlen + (t)); }

// Stage window into per-wave LDS buffer (32 ds_write_b32, banks 2-way free)
#define STAGE(G) { asm volatile("" ::: "memory");  _Pragma("unroll")          \
    for (int r = 0; r < 8; ++r) {                                             \
        int b8 = (8 * r + srow) * SROW + scol;                                \
        sb[b8] = G[r].x; sb[b8+1] = G[r].y; sb[b8+2] = G[r].z;                \
        sb[b8+3] = G[r].w; }                                                  \
    ds_fence(); }

// Batch the lane's 32-step u window into registers: ONE wait per window.
#define READBACK() { asm volatile("" ::: "memory"); _Pragma("unroll")         \
    for (int j = 0; j < 32; ++j) U[j] = sb[lbase + j];                        \
    ds_fence(); }

// Flush 64 z-cols for the wave's 64 rows through sb (sb must be free).
#define FLUSH(h) { const int cb = t_out + 1 + 64 * (h);                       \
    _Pragma("unroll") for (int p = 0; p < 2; ++p) {                           \
        asm volatile("" ::: "memory");                                        \
        _Pragma("unroll") for (int j = 0; j < 32; ++j)                        \
            sb[lbase + j] = zz[p * 32 + j];                                   \
        ds_fence();                                                           \
        _Pragma("unroll") for (int kk = 0; kk < 32; ++kk) {                   \
            int row = 2 * kk + rh;                                            \
            out[(size_t)(rowb + row) * TP1 + cb + p * 32 + col] =             \
                sb[row * SROW + col];                                         \
        }                                                                     \
        ds_fence(); } }

__global__ __launch_bounds__(BLOCK, 2) void sim_kernel(const float* __restrict__ u,
                                                       const float* __restrict__ ws,
                                                       float* __restrict__ out) {
    __shared__ float s_st[4][64 * SROW];           // 4 x 8.4 KB per-wave bufs
    const int tid = threadIdx.x;
    const int w   = tid >> 6;                      // wave id (4)
    const int l   = tid & 63;                      // lane
    float* sb = s_st[w];

    const int c    = blockIdx.x >> 5;              // chunk id (16)
    const int bb   = blockIdx.x & 31;              // row-block id (32)
    const int rowb = bb * 256 + w * 64;            // wave's first row
    const int t_out   = c * CLEN;                  // first owned step
    const int t_begin = (t_out >= WARM) ? (t_out - WARM) : 0;   // c=0 -> 0

    // staging lane map: lane l covers row srow of each 8-row group,
    // 16 B at float offset scol within the 32-step window
    const int srow = l >> 3;                       // 0..7
    const int scol = (l & 7) * 4;                  // 0,4,...,28
    const float* __restrict__ up = u + (size_t)(rowb + srow) * Tlen + scol;
    const int lbase = l * SROW;

    // Issue the first window FIRST so cold misses start immediately.
    float4 G[8];
    GLOAD(G, t_begin);

    // Chebyshev coefficients (wave-uniform VGPRs)
    const float4* ws4 = (const float4*)ws;
    float4 cA = ws4[0], cB = ws4[1], cC = ws4[2], cD = ws4[3];

    // Prime: sb = window(t_begin), G = window(t_begin+32)
    STAGE(G);
    GLOAD(G, t_begin + 32);

    float k1 = 0.f, k2 = 0.f, v = 0.f;
    float U[32];                                   // register u window

    // ---------------- warmup: 0 or 4 windows, z discarded ----------------
    for (int tb = t_begin; tb < t_out; tb += 32) {
        READBACK();                                // U <- window(tb)
        STAGE(G);                                  // sb <- window(tb+32)
        GLOAD(G, tb + 64);                         // <= t_out+32 <= 1952 ok
        #pragma unroll
        for (int t2 = 0; t2 < 32; ++t2)
            step_one(U[t2], k1, k2, v, cA, cB, cC, cD);
    }

    // ---------------- output: 4 windows of 32 steps ----------------
    const int col = l & 31;                        // flush col lane
    const int rh  = l >> 5;                        // flush row half (0/1)
    float zz[64];
    #pragma unroll
    for (int k = 0; k < 4; ++k) {
        const int tb = t_out + 32 * k;
        READBACK();                                // U <- window(tb); sb free
        if (k == 2) FLUSH(0);                      // cols [t_out+1, +65)
        STAGE(G);                                  // sb <- window(tb+32)
        int tn = tb + 64;                          // clamp: tail of c=15
        if (tn > Tlen - 32) tn = Tlen - 32;
        GLOAD(G, tn);
        #pragma unroll
        for (int t2 = 0; t2 < 32; ++t2)
            zz[(k & 1) * 32 + t2] = step_one(U[t2], k1, k2, v, cA, cB, cC, cD);
    }
    FLUSH(1);                                      // cols [t_out+65, +129)
}

// ------------------------------ launcher -----------------------------------
extern "C" void kernel_launch(void* const* d_in, const int* in_sizes, int n_in,
                              void* d_out, int out_size, void* d_ws, size_t ws_size,
                              hipStream_t stream) {
    const float* u = (const float*)d_in[0];
    float* out = (float*)d_out;
    float* ws  = (float*)d_ws;                     // needs 64 B (16 coeffs)
    setup_kernel<<<32, 256, 0, stream>>>(ws, out);
    sim_kernel<<<SIM_GRID, BLOCK, 0, stream>>>(u, ws, out);
}